// Round 1
// baseline (472.689 us; speedup 1.0000x reference)
//
#include <hip/hip_runtime.h>
#include <stdint.h>

#define DEV __device__ __forceinline__

constexpr int nB = 64;
constexpr int nL = 1024;
constexpr int nD = 2048;
constexpr int nH = 128;

constexpr int NT = 16;          // L tiles for mean
constexpr int LT = nL / NT;     // 64 rows per tile
constexpr int NC = 32;          // d-chunks
constexpr int CD = nD / NC;     // 64 d per chunk
constexpr int NBG = 16;         // batch groups
constexpr int BG = nB / NBG;    // 4 batches per group

constexpr size_t X_ELEMS = (size_t)nB * (size_t)nL * (size_t)nD;  // 134217728

// ---------- math helpers (match JAX/XLA fp32 semantics closely) ----------
DEV float gelu_f(float x) {
  return 0.5f * x * (1.0f + erff(x * 0.7071067811865476f));
}
DEV float gelu_grad_f(float x) {
  return 0.5f * (1.0f + erff(x * 0.7071067811865476f))
       + x * 0.3989422804014327f * expf(-0.5f * x * x);
}
DEV float sigmoid_f(float x) { return 1.0f / (1.0f + expf(-x)); }

DEV uint32_t rotl32(uint32_t v, int r) { return (v << r) | (v >> (32 - r)); }

// Threefry-2x32 with key (0,1)  == jax.random.key(1)
DEV void threefry_key01(uint32_t& x0, uint32_t& x1) {
  const uint32_t ks0 = 0u, ks1 = 1u, ks2 = 0x1BD11BDAu ^ 0u ^ 1u;
  x0 += ks0; x1 += ks1;
#define TF_RND(r) { x0 += x1; x1 = rotl32(x1, (r)); x1 ^= x0; }
  TF_RND(13) TF_RND(15) TF_RND(26) TF_RND(6)
  x0 += ks1; x1 += ks2 + 1u;
  TF_RND(17) TF_RND(29) TF_RND(16) TF_RND(24)
  x0 += ks2; x1 += ks0 + 2u;
  TF_RND(13) TF_RND(15) TF_RND(26) TF_RND(6)
  x0 += ks0; x1 += ks1 + 3u;
  TF_RND(17) TF_RND(29) TF_RND(16) TF_RND(24)
  x0 += ks1; x1 += ks2 + 4u;
  TF_RND(13) TF_RND(15) TF_RND(26) TF_RND(6)
  x0 += ks2; x1 += ks0 + 5u;
#undef TF_RND
}

// XLA ErfInv32 (Giles single-precision polynomial)
DEV float erfinv_f32(float x) {
  float w = -log1pf(-x * x);
  float p;
  if (w < 5.0f) {
    w -= 2.5f;
    p = 2.81022636e-08f;
    p = fmaf(p, w, 3.43273939e-07f);
    p = fmaf(p, w, -3.5233877e-06f);
    p = fmaf(p, w, -4.39150654e-06f);
    p = fmaf(p, w, 0.00021858087f);
    p = fmaf(p, w, -0.00125372503f);
    p = fmaf(p, w, -0.00417768164f);
    p = fmaf(p, w, 0.246640727f);
    p = fmaf(p, w, 1.50140941f);
  } else {
    w = sqrtf(w) - 3.0f;
    p = -0.000200214257f;
    p = fmaf(p, w, 0.000100950558f);
    p = fmaf(p, w, 0.00134934322f);
    p = fmaf(p, w, -0.00367342844f);
    p = fmaf(p, w, 0.00573950773f);
    p = fmaf(p, w, -0.0076224613f);
    p = fmaf(p, w, 0.00943887047f);
    p = fmaf(p, w, 1.00167406f);
    p = fmaf(p, w, 2.83297682f);
  }
  return p * x;
}

// jax.random.normal(key(1), (64,2048), f32), element i of row-major flat array
DEV float jax_normal_key1(int i) {
  const uint32_t j = (uint32_t)(i & 0xFFFF);
  uint32_t x0 = j, x1 = j + 65536u;
  threefry_key01(x0, x1);
  const uint32_t bits = (i < 65536) ? x0 : x1;
  const float u01 = __uint_as_float((bits >> 9) | 0x3F800000u) - 1.0f;
  const float lo = __uint_as_float(0xBF7FFFFFu);   // nextafter(-1,0)
  float v = u01 * 2.0f + lo;
  v = fmaxf(lo, v);
  return 1.4142135623730951f * erfinv_f32(v);
}

// ---------- K1: fused copy x->out + deterministic partial mean ----------
__global__ __launch_bounds__(256) void k_copy_mean(
    const float* __restrict__ x, float* __restrict__ out,
    float* __restrict__ pmean)
{
  const int blk = blockIdx.x;
  const int b = blk / NT, tile = blk % NT;
  const int t = threadIdx.x;
  const size_t d0 = (size_t)t * 8;
  const size_t base = ((size_t)b * nL + (size_t)tile * LT) * nD + d0;
  float a[8] = {0.f,0.f,0.f,0.f,0.f,0.f,0.f,0.f};
  for (int l = 0; l < LT; ++l) {
    const float4* p = reinterpret_cast<const float4*>(x + base + (size_t)l * nD);
    float4 v0 = p[0], v1 = p[1];
    float4* qo = reinterpret_cast<float4*>(out + base + (size_t)l * nD);
    qo[0] = v0; qo[1] = v1;
    a[0]+=v0.x; a[1]+=v0.y; a[2]+=v0.z; a[3]+=v0.w;
    a[4]+=v1.x; a[5]+=v1.y; a[6]+=v1.z; a[7]+=v1.w;
  }
  float* pm = pmean + ((size_t)(b * NT + tile)) * nD + d0;
  float4 o0 = make_float4(a[0],a[1],a[2],a[3]);
  float4 o1 = make_float4(a[4],a[5],a[6],a[7]);
  reinterpret_cast<float4*>(pm)[0] = o0;
  reinterpret_cast<float4*>(pm)[1] = o1;
}

// fallback when ws is small: atomic accumulate directly into pooled
__global__ __launch_bounds__(256) void k_copy_mean_atomic(
    const float* __restrict__ x, float* __restrict__ out,
    float* __restrict__ pooled)
{
  const int blk = blockIdx.x;
  const int b = blk / NT, tile = blk % NT;
  const int t = threadIdx.x;
  const size_t d0 = (size_t)t * 8;
  const size_t base = ((size_t)b * nL + (size_t)tile * LT) * nD + d0;
  float a[8] = {0.f,0.f,0.f,0.f,0.f,0.f,0.f,0.f};
  for (int l = 0; l < LT; ++l) {
    const float4* p = reinterpret_cast<const float4*>(x + base + (size_t)l * nD);
    float4 v0 = p[0], v1 = p[1];
    float4* qo = reinterpret_cast<float4*>(out + base + (size_t)l * nD);
    qo[0] = v0; qo[1] = v1;
    a[0]+=v0.x; a[1]+=v0.y; a[2]+=v0.z; a[3]+=v0.w;
    a[4]+=v1.x; a[5]+=v1.y; a[6]+=v1.z; a[7]+=v1.w;
  }
  float* pp = pooled + (size_t)b * nD + d0;
  const float sc = 1.0f / nL;
  for (int k2 = 0; k2 < 8; ++k2) atomicAdd(&pp[k2], a[k2] * sc);
}

// ---------- K2: pooled reduce + threefry noise + xa0 + first fwd partials ----------
__global__ __launch_bounds__(128) void k_init_fwd0(
    const float* __restrict__ W1, const float* __restrict__ pmean,
    float* __restrict__ pooled, float* __restrict__ xa,
    float* __restrict__ pz, const int from_partial)
{
  __shared__ float w1s[CD][nH + 1];
  __shared__ float xaL[BG][CD];
  const int t = threadIdx.x;       // 0..127
  const int g = blockIdx.x;        // batch group 0..15
  const int c = blockIdx.y;        // d-chunk 0..31

  for (int k = 0; k < CD; ++k)
    w1s[k][t] = W1[(size_t)(c * CD + k) * nH + t];

  const int dl = t & (CD - 1);     // 0..63
  const int hf = t >> 6;           // 0..1
  const int d = c * CD + dl;
  for (int jj = 0; jj < 2; ++jj) {
    const int j = 2 * hf + jj;
    const int b = g * BG + j;
    const size_t idx = (size_t)b * nD + d;
    float pl;
    if (from_partial) {
      float s = 0.f;
      for (int nt = 0; nt < NT; ++nt)
        s += pmean[(size_t)(b * NT + nt) * nD + d];
      pl = s * (1.0f / nL);
      pooled[idx] = pl;
    } else {
      pl = pooled[idx];
    }
    const int i = b * nD + d;
    const float nz = jax_normal_key1(i);
    const float xv = pl + 0.01f * nz;
    xa[idx] = xv;
    xaL[j][dl] = xv;
  }
  __syncthreads();
  for (int j = 0; j < BG; ++j) {
    const int b = g * BG + j;
    float acc = 0.f;
    for (int r = 0; r < CD; ++r)
      acc += xaL[j][r] * w1s[r][t];
    pz[(size_t)(c * nB + b) * nH + t] = acc;
  }
}

// ---------- K3 (x10): one PGD step ----------
// Phase A: reduce z1 partials -> sigmoid -> dz1 (redundant per block, cheap)
// Phase C: g = dz1 . W1row (LDS), sign update of xa
// Phase D: fwd partials for next iteration with same LDS W1 chunk
__global__ __launch_bounds__(128) void k_iter(
    const float* __restrict__ W1, const float* __restrict__ b1,
    const float* __restrict__ W2, const float* __restrict__ b2,
    const float* __restrict__ pooled, float* __restrict__ xa,
    const float* __restrict__ pz_r, float* __restrict__ pz_w)
{
  __shared__ float w1s[CD][nH + 1];
  __shared__ float xaL[BG][CD];
  __shared__ float dz1L[BG][nH];
  __shared__ float red[BG][nH];

  const int t = threadIdx.x;       // 0..127 (= h in phases A/D)
  const int g = blockIdx.x;        // 0..15
  const int c = blockIdx.y;        // 0..31

  // W1 chunk -> LDS (first used after the phase-A barriers)
  for (int k = 0; k < CD; ++k)
    w1s[k][t] = W1[(size_t)(c * CD + k) * nH + t];

  // Phase A
  float z1r[BG];
  const float w2t = W2[t];
  const float b1t = b1[t];
  for (int j = 0; j < BG; ++j) {
    const int b = g * BG + j;
    float z = 0.f;
    for (int cc = 0; cc < NC; ++cc)
      z += pz_r[(size_t)(cc * nB + b) * nH + t];
    z += b1t;
    z1r[j] = z;
    red[j][t] = gelu_f(z) * w2t;
  }
  __syncthreads();
  for (int s = 64; s > 0; s >>= 1) {
    if (t < s) {
      for (int j = 0; j < BG; ++j) red[j][t] += red[j][t + s];
    }
    __syncthreads();
  }
  const float b2v = b2[0];
  for (int j = 0; j < BG; ++j) {
    const float sg = sigmoid_f(red[j][0] + b2v);
    const float cj = sg * (1.0f - sg);
    dz1L[j][t] = cj * w2t * gelu_grad_f(z1r[j]);
  }
  __syncthreads();

  // Phase C: backward + sign update (thread -> (d_local, 2 batches))
  const int dl = t & (CD - 1);
  const int hf = t >> 6;
  float ga0 = 0.f, ga1 = 0.f;
  for (int h = 0; h < nH; ++h) {
    const float wv = w1s[dl][h];
    ga0 += dz1L[2 * hf + 0][h] * wv;
    ga1 += dz1L[2 * hf + 1][h] * wv;
  }
  const int d = c * CD + dl;
  for (int jj = 0; jj < 2; ++jj) {
    const int j = 2 * hf + jj;
    const int b = g * BG + j;
    const size_t idx = (size_t)b * nD + d;
    const float gv = (jj == 0) ? ga0 : ga1;
    const float sgn = (gv > 0.f) ? 1.f : ((gv < 0.f) ? -1.f : 0.f);
    float xv = xa[idx] - 0.01f * sgn;
    const float pl = pooled[idx];
    float delta = xv - pl;
    delta = fminf(fmaxf(delta, -0.2f), 0.2f);
    xv = pl + delta;
    xa[idx] = xv;
    xaL[j][dl] = xv;
  }
  __syncthreads();

  // Phase D: fwd partials for next iteration (thread = h again)
  for (int j = 0; j < BG; ++j) {
    const int b = g * BG + j;
    float acc = 0.f;
    for (int r = 0; r < CD; ++r)
      acc += xaL[j][r] * w1s[r][t];
    pz_w[(size_t)(c * nB + b) * nH + t] = acc;
  }
}

// ---------- K4: final score + outputs ----------
__global__ __launch_bounds__(256) void k_final(
    const float* __restrict__ b1, const float* __restrict__ W2,
    const float* __restrict__ b2, const float* __restrict__ pz,
    float* __restrict__ out)
{
  __shared__ float sArr[nB];
  const int t = threadIdx.x;
  const int b = t >> 2;            // 0..63
  const int q = t & 3;             // h quarter
  float part = 0.f;
  for (int k = 0; k < 32; ++k) {
    const int h = q * 32 + k;
    float z = 0.f;
    for (int cc = 0; cc < NC; ++cc)
      z += pz[(size_t)(cc * nB + b) * nH + h];
    z += b1[h];
    part += gelu_f(z) * W2[h];
  }
  part += __shfl_xor(part, 1, 64);
  part += __shfl_xor(part, 2, 64);
  if (q == 0) sArr[b] = sigmoid_f(part + b2[0]);
  __syncthreads();
  if (t < nB) {
    const float s = sArr[t];
    out[X_ELEMS + t] = s;                 // worst_score
    out[X_ELEMS + nB + t] = 1.0f - s;     // cert_score
    float m = s;
    for (int o = 32; o > 0; o >>= 1) m = fminf(m, __shfl_xor(m, o, 64));
    if (t == 0) out[X_ELEMS + 2 * nB] = (m < 0.1f) ? 1.0f : 0.0f;  // violated
  }
}

extern "C" void kernel_launch(void* const* d_in, const int* in_sizes, int n_in,
                              void* d_out, int out_size, void* d_ws, size_t ws_size,
                              hipStream_t stream) {
  const float* x  = (const float*)d_in[0];
  const float* W1 = (const float*)d_in[1];
  const float* b1 = (const float*)d_in[2];
  const float* W2 = (const float*)d_in[3];
  const float* b2 = (const float*)d_in[4];
  float* out = (float*)d_out;
  float* ws = (float*)d_ws;

  constexpr size_t PMEAN_ELEMS  = (size_t)nB * NT * nD;   // 2,097,152
  constexpr size_t POOLED_ELEMS = (size_t)nB * nD;        // 131,072
  constexpr size_t PZ_ELEMS     = (size_t)NC * nB * nH;   // 262,144
  const size_t primary_bytes =
      (PMEAN_ELEMS + POOLED_ELEMS * 2 + PZ_ELEMS * 2) * sizeof(float);
  const bool primary = ws_size >= primary_bytes;

  float *pmean, *pooled;
  if (primary) { pmean = ws; pooled = ws + PMEAN_ELEMS; }
  else         { pmean = nullptr; pooled = ws; }
  float* xa  = pooled + POOLED_ELEMS;
  float* pzA = xa + POOLED_ELEMS;
  float* pzB = pzA + PZ_ELEMS;

  if (primary) {
    k_copy_mean<<<nB * NT, 256, 0, stream>>>(x, out, pmean);
  } else {
    hipMemsetAsync(pooled, 0, POOLED_ELEMS * sizeof(float), stream);
    k_copy_mean_atomic<<<nB * NT, 256, 0, stream>>>(x, out, pooled);
  }

  dim3 grid(NBG, NC);
  k_init_fwd0<<<grid, 128, 0, stream>>>(W1, pmean, pooled, xa, pzA,
                                        primary ? 1 : 0);
  for (int it = 0; it < 10; ++it) {
    const float* pr = (it & 1) ? pzB : pzA;
    float*       pw = (it & 1) ? pzA : pzB;
    k_iter<<<grid, 128, 0, stream>>>(W1, b1, W2, b2, pooled, xa, pr, pw);
  }
  k_final<<<1, 256, 0, stream>>>(b1, W2, b2, pzA, out);
}

// Round 2
// 467.710 us; speedup vs baseline: 1.0106x; 1.0106x over previous
//
#include <hip/hip_runtime.h>
#include <stdint.h>

#define DEV __device__ __forceinline__

constexpr int nB = 64;
constexpr int nL = 1024;
constexpr int nD = 2048;
constexpr int nH = 128;

constexpr int NT = 16;          // L tiles for mean
constexpr int LT = nL / NT;     // 64 rows per tile

constexpr size_t X_ELEMS = (size_t)nB * (size_t)nL * (size_t)nD;  // 134217728

// ---------- math helpers (match JAX/XLA fp32 semantics closely) ----------
DEV float gelu_f(float x) {
  return 0.5f * x * (1.0f + erff(x * 0.7071067811865476f));
}
DEV float gelu_grad_f(float x) {
  return 0.5f * (1.0f + erff(x * 0.7071067811865476f))
       + x * 0.3989422804014327f * expf(-0.5f * x * x);
}
DEV float sigmoid_f(float x) { return 1.0f / (1.0f + expf(-x)); }

DEV uint32_t rotl32(uint32_t v, int r) { return (v << r) | (v >> (32 - r)); }

// Threefry-2x32 with key (0,1)  == jax.random.key(1)
DEV void threefry_key01(uint32_t& x0, uint32_t& x1) {
  const uint32_t ks0 = 0u, ks1 = 1u, ks2 = 0x1BD11BDAu ^ 0u ^ 1u;
  x0 += ks0; x1 += ks1;
#define TF_RND(r) { x0 += x1; x1 = rotl32(x1, (r)); x1 ^= x0; }
  TF_RND(13) TF_RND(15) TF_RND(26) TF_RND(6)
  x0 += ks1; x1 += ks2 + 1u;
  TF_RND(17) TF_RND(29) TF_RND(16) TF_RND(24)
  x0 += ks2; x1 += ks0 + 2u;
  TF_RND(13) TF_RND(15) TF_RND(26) TF_RND(6)
  x0 += ks0; x1 += ks1 + 3u;
  TF_RND(17) TF_RND(29) TF_RND(16) TF_RND(24)
  x0 += ks1; x1 += ks2 + 4u;
  TF_RND(13) TF_RND(15) TF_RND(26) TF_RND(6)
  x0 += ks2; x1 += ks0 + 5u;
#undef TF_RND
}

// XLA ErfInv32 (Giles single-precision polynomial)
DEV float erfinv_f32(float x) {
  float w = -log1pf(-x * x);
  float p;
  if (w < 5.0f) {
    w -= 2.5f;
    p = 2.81022636e-08f;
    p = fmaf(p, w, 3.43273939e-07f);
    p = fmaf(p, w, -3.5233877e-06f);
    p = fmaf(p, w, -4.39150654e-06f);
    p = fmaf(p, w, 0.00021858087f);
    p = fmaf(p, w, -0.00125372503f);
    p = fmaf(p, w, -0.00417768164f);
    p = fmaf(p, w, 0.246640727f);
    p = fmaf(p, w, 1.50140941f);
  } else {
    w = sqrtf(w) - 3.0f;
    p = -0.000200214257f;
    p = fmaf(p, w, 0.000100950558f);
    p = fmaf(p, w, 0.00134934322f);
    p = fmaf(p, w, -0.00367342844f);
    p = fmaf(p, w, 0.00573950773f);
    p = fmaf(p, w, -0.0076224613f);
    p = fmaf(p, w, 0.00943887047f);
    p = fmaf(p, w, 1.00167406f);
    p = fmaf(p, w, 2.83297682f);
  }
  return p * x;
}

// jax.random.normal(key(1), (64,2048), f32), element i of row-major flat array
DEV float jax_normal_key1(int i) {
  const uint32_t j = (uint32_t)(i & 0xFFFF);
  uint32_t x0 = j, x1 = j + 65536u;
  threefry_key01(x0, x1);
  const uint32_t bits = (i < 65536) ? x0 : x1;
  const float u01 = __uint_as_float((bits >> 9) | 0x3F800000u) - 1.0f;
  const float lo = __uint_as_float(0xBF7FFFFFu);   // nextafter(-1,0)
  float v = u01 * 2.0f + lo;
  v = fmaxf(lo, v);
  return 1.4142135623730951f * erfinv_f32(v);
}

// ---------- K1: fused copy x->out + deterministic partial mean ----------
// lane-contiguous float4: lane i <-> bytes [16i,16i+16) per instruction
__global__ __launch_bounds__(256) void k_copy_mean(
    const float* __restrict__ x, float* __restrict__ out,
    float* __restrict__ pmean)
{
  const int blk = blockIdx.x;            // = b*16 + tile
  const int t = threadIdx.x;
  const size_t base = (size_t)blk * LT * nD;
  const size_t o0 = (size_t)4 * t;       // d in [0,1024)
  const size_t o1 = 1024 + (size_t)4 * t;
  float4 a0 = make_float4(0.f,0.f,0.f,0.f);
  float4 a1 = make_float4(0.f,0.f,0.f,0.f);
  for (int l = 0; l < LT; ++l) {
    const size_t r = base + (size_t)l * nD;
    const float4 v0 = *reinterpret_cast<const float4*>(x + r + o0);
    const float4 v1 = *reinterpret_cast<const float4*>(x + r + o1);
    *reinterpret_cast<float4*>(out + r + o0) = v0;
    *reinterpret_cast<float4*>(out + r + o1) = v1;
    a0.x += v0.x; a0.y += v0.y; a0.z += v0.z; a0.w += v0.w;
    a1.x += v1.x; a1.y += v1.y; a1.z += v1.z; a1.w += v1.w;
  }
  float* pm = pmean + (size_t)blk * nD;
  *reinterpret_cast<float4*>(pm + o0) = a0;
  *reinterpret_cast<float4*>(pm + o1) = a1;
}

// fallback when ws is small: atomic accumulate directly into pooled
__global__ __launch_bounds__(256) void k_copy_mean_atomic(
    const float* __restrict__ x, float* __restrict__ out,
    float* __restrict__ pooled)
{
  const int blk = blockIdx.x;
  const int b = blk >> 4;
  const int t = threadIdx.x;
  const size_t base = (size_t)blk * LT * nD;
  const size_t o0 = (size_t)4 * t;
  const size_t o1 = 1024 + (size_t)4 * t;
  float4 a0 = make_float4(0.f,0.f,0.f,0.f);
  float4 a1 = make_float4(0.f,0.f,0.f,0.f);
  for (int l = 0; l < LT; ++l) {
    const size_t r = base + (size_t)l * nD;
    const float4 v0 = *reinterpret_cast<const float4*>(x + r + o0);
    const float4 v1 = *reinterpret_cast<const float4*>(x + r + o1);
    *reinterpret_cast<float4*>(out + r + o0) = v0;
    *reinterpret_cast<float4*>(out + r + o1) = v1;
    a0.x += v0.x; a0.y += v0.y; a0.z += v0.z; a0.w += v0.w;
    a1.x += v1.x; a1.y += v1.y; a1.z += v1.z; a1.w += v1.w;
  }
  float* pp = pooled + (size_t)b * nD;
  const float sc = 1.0f / nL;
  atomicAdd(&pp[o0+0], a0.x*sc); atomicAdd(&pp[o0+1], a0.y*sc);
  atomicAdd(&pp[o0+2], a0.z*sc); atomicAdd(&pp[o0+3], a0.w*sc);
  atomicAdd(&pp[o1+0], a1.x*sc); atomicAdd(&pp[o1+1], a1.y*sc);
  atomicAdd(&pp[o1+2], a1.z*sc); atomicAdd(&pp[o1+3], a1.w*sc);
}

// ---------- K0: W1 [2048,128] -> W1T [128,2048] ----------
__global__ __launch_bounds__(256) void k_transpose(
    const float* __restrict__ W1, float* __restrict__ W1T)
{
  __shared__ float tile[64][65];
  const int bd = blockIdx.x;   // 0..31  (d block of 64)
  const int bh = blockIdx.y;   // 0..1   (h block of 64)
  const int t = threadIdx.x;
  const int j = t & 63;
  const int i0 = (t >> 6) * 16;
  for (int ii = 0; ii < 16; ++ii) {
    const int i = i0 + ii;
    tile[i][j] = W1[(size_t)(bd * 64 + i) * nH + bh * 64 + j];
  }
  __syncthreads();
  for (int ii = 0; ii < 16; ++ii) {
    const int i = i0 + ii;     // i = h-local, j = d-local
    W1T[(size_t)(bh * 64 + i) * nD + bd * 64 + j] = tile[j][i];
  }
}

// ---------- K2: whole PGD loop, one block per batch ----------
// Batches are independent under score.sum() grad, so no inter-block traffic.
// xa, pooled live in LDS; W1 (fwd) and W1T (bwd) stream from L2 each pass.
__global__ __launch_bounds__(1024) void k_pgd(
    const float* __restrict__ W1, const float* __restrict__ W1T,
    const float* __restrict__ b1, const float* __restrict__ W2,
    const float* __restrict__ b2, const float* __restrict__ pmean,
    const float* __restrict__ pooledG, float* __restrict__ scores,
    const int from_partial)
{
  __shared__ float xaS[nD];
  __shared__ float pooledS[nD];
  __shared__ float red[8][nH];
  __shared__ float dz1S[nH];
  __shared__ float red2[2];

  const int t = threadIdx.x;       // 0..1023
  const int b = blockIdx.x;        // 0..63
  const int h = t & (nH - 1);      // 0..127
  const int dq = t >> 7;           // 0..7

  // init: pooled reduce + threefry noise -> xa0
  float2 pl;
  if (from_partial) {
    float2 s = make_float2(0.f, 0.f);
    for (int nt = 0; nt < NT; ++nt) {
      const float2 v = *reinterpret_cast<const float2*>(
          &pmean[((size_t)(b * NT + nt)) * nD + 2 * t]);
      s.x += v.x; s.y += v.y;
    }
    pl = make_float2(s.x * (1.0f / nL), s.y * (1.0f / nL));
  } else {
    pl = *reinterpret_cast<const float2*>(&pooledG[(size_t)b * nD + 2 * t]);
  }
  pooledS[2 * t]     = pl.x;
  pooledS[2 * t + 1] = pl.y;
  const int i0 = b * nD + 2 * t;
  xaS[2 * t]     = pl.x + 0.01f * jax_normal_key1(i0);
  xaS[2 * t + 1] = pl.y + 0.01f * jax_normal_key1(i0 + 1);

  const float b1t = (t < nH) ? b1[t] : 0.f;
  const float w2t = (t < nH) ? W2[t] : 0.f;
  const float b2s = b2[0];
  const float2* __restrict__ w1t2 = reinterpret_cast<const float2*>(W1T);

  __syncthreads();

  float sig_last = 0.f;
  for (int it = 0; it <= 10; ++it) {
    // ---- forward: z1 partials (thread = (h, d-octant)) ----
    float acc = 0.f;
    const float* __restrict__ w1p = W1 + (size_t)(dq * 256) * nH + h;
    #pragma unroll 8
    for (int d = 0; d < 256; ++d)
      acc = fmaf(xaS[dq * 256 + d], w1p[(size_t)d * nH], acc);
    red[dq][h] = acc;
    __syncthreads();

    float z1 = 0.f;
    if (t < nH) {
      #pragma unroll
      for (int q = 0; q < 8; ++q) z1 += red[q][t];
      z1 += b1t;
      float part = gelu_f(z1) * w2t;
      #pragma unroll
      for (int m = 1; m <= 32; m <<= 1) part += __shfl_xor(part, m, 64);
      if ((t & 63) == 0) red2[t >> 6] = part;
    }
    __syncthreads();

    const float z2 = red2[0] + red2[1] + b2s;
    const float sig = sigmoid_f(z2);
    if (it == 10) { sig_last = sig; break; }

    if (t < nH) dz1S[t] = sig * (1.f - sig) * w2t * gelu_grad_f(z1);
    __syncthreads();

    // ---- backward: g = W1 . dz1  (thread = d pair, via W1T) ----
    float gx = 0.f, gy = 0.f;
    #pragma unroll 8
    for (int hh = 0; hh < nH; ++hh) {
      const float dz = dz1S[hh];
      const float2 w = w1t2[(size_t)hh * (nD / 2) + t];
      gx = fmaf(dz, w.x, gx);
      gy = fmaf(dz, w.y, gy);
    }

    // ---- PGD sign update + eps clip (in LDS) ----
    const float sg0 = (gx > 0.f) ? 1.f : ((gx < 0.f) ? -1.f : 0.f);
    const float sg1 = (gy > 0.f) ? 1.f : ((gy < 0.f) ? -1.f : 0.f);
    float xv0 = xaS[2 * t]     - 0.01f * sg0;
    float xv1 = xaS[2 * t + 1] - 0.01f * sg1;
    const float p0 = pooledS[2 * t], p1 = pooledS[2 * t + 1];
    float d0 = fminf(fmaxf(xv0 - p0, -0.2f), 0.2f);
    float d1 = fminf(fmaxf(xv1 - p1, -0.2f), 0.2f);
    xaS[2 * t]     = p0 + d0;
    xaS[2 * t + 1] = p1 + d1;
    __syncthreads();
  }

  if (t == 0) scores[b] = sig_last;
}

// ---------- K3: tail outputs ----------
__global__ __launch_bounds__(64) void k_finalize(
    const float* __restrict__ scores, float* __restrict__ out)
{
  const int t = threadIdx.x;  // 0..63
  const float s = scores[t];
  out[X_ELEMS + t] = s;                    // worst_score
  out[X_ELEMS + nB + t] = 1.0f - s;        // cert_score
  float m = s;
  for (int o = 32; o > 0; o >>= 1) m = fminf(m, __shfl_xor(m, o, 64));
  if (t == 0) out[X_ELEMS + 2 * nB] = (m < 0.1f) ? 1.0f : 0.0f;  // violated
}

extern "C" void kernel_launch(void* const* d_in, const int* in_sizes, int n_in,
                              void* d_out, int out_size, void* d_ws, size_t ws_size,
                              hipStream_t stream) {
  const float* x  = (const float*)d_in[0];
  const float* W1 = (const float*)d_in[1];
  const float* b1 = (const float*)d_in[2];
  const float* W2 = (const float*)d_in[3];
  const float* b2 = (const float*)d_in[4];
  float* out = (float*)d_out;
  float* ws = (float*)d_ws;

  constexpr size_t PMEAN_ELEMS  = (size_t)nB * NT * nD;   // 2,097,152
  constexpr size_t POOLED_ELEMS = (size_t)nB * nD;        // 131,072
  constexpr size_t W1T_ELEMS    = (size_t)nD * nH;        // 262,144
  const size_t primary_bytes = (PMEAN_ELEMS + W1T_ELEMS + nB) * sizeof(float);
  const bool primary = ws_size >= primary_bytes;

  float *pmean, *pooled, *w1t, *scores;
  if (primary) {
    pmean  = ws;
    pooled = nullptr;
    w1t    = ws + PMEAN_ELEMS;
    scores = w1t + W1T_ELEMS;
  } else {
    pmean  = nullptr;
    pooled = ws;
    w1t    = ws + POOLED_ELEMS;
    scores = w1t + W1T_ELEMS;
  }

  if (primary) {
    k_copy_mean<<<nB * NT, 256, 0, stream>>>(x, out, pmean);
  } else {
    hipMemsetAsync(pooled, 0, POOLED_ELEMS * sizeof(float), stream);
    k_copy_mean_atomic<<<nB * NT, 256, 0, stream>>>(x, out, pooled);
  }

  k_transpose<<<dim3(32, 2), 256, 0, stream>>>(W1, w1t);

  k_pgd<<<nB, 1024, 0, stream>>>(W1, w1t, b1, W2, b2,
                                 primary ? pmean : ws, primary ? ws : pooled,
                                 scores, primary ? 1 : 0);

  k_finalize<<<1, 64, 0, stream>>>(scores, out);
}